// Round 1
// baseline (287.075 us; speedup 1.0000x reference)
//
#include <hip/hip_runtime.h>

// Problem constants (from reference)
#define COLS    2048
#define CPC     32          // cells per column == 32 bits -> one word per column
#define NCELLS  65536       // COLS * CPC
#define SEGS    16
#define SYN     32
#define THRESH  13

#define CPW     16                     // cells per wave (pipelined)
#define CPB     (4 * CPW)              // 64 cells per block (4 waves)
#define PREDICT_GRID (NCELLS / CPB)    // 1024 blocks -> exactly 4 resident/CU

// ---------------------------------------------------------------------------
// Kernel 1: active-cell phase (unchanged — correct, tiny, atomic-free).
// ---------------------------------------------------------------------------
__global__ __launch_bounds__(256) void tm_active_kernel(
    const float* __restrict__ active_columns,
    const float* __restrict__ prev_predictive,
    float* __restrict__ out_active,
    unsigned int* __restrict__ ws_mask,
    unsigned char* __restrict__ ws_flags)
{
    int n = blockIdx.x * 256 + threadIdx.x;   // cell index, grid is exact
    int c = n >> 5;                            // column
    int j = n & 31;                            // cell within column
    int lane = threadIdx.x & 63;

    bool predbit    = prev_predictive[n] > 0.0f;
    bool col_active = active_columns[c] > 0.0f;

    unsigned long long pb = __ballot(predbit);
    unsigned int colmask = (lane < 32) ? (unsigned int)pb : (unsigned int)(pb >> 32);
    bool has_pred = (colmask != 0u);

    bool active = col_active && (has_pred ? predbit : true);
    out_active[n] = active ? 1.0f : 0.0f;

    unsigned long long ab = __ballot(active);
    if (lane == 0)  ws_mask[c] = (unsigned int)ab;
    if (lane == 32) ws_mask[c] = (unsigned int)(ab >> 32);

    if (j == 0)
        ws_flags[c] = (unsigned char)((col_active ? 1 : 0) |
                                      ((col_active && has_pred) ? 2 : 0));
}

// ---------------------------------------------------------------------------
// Async global->LDS DMA, 1 KB per wave-instruction: lane i's 16 B from
// g + i*16 lands at lds + i*16 (wave-uniform LDS base + lane*size — m104).
// ---------------------------------------------------------------------------
typedef const __attribute__((address_space(1))) void* gas_ptr;
typedef __attribute__((address_space(3)))       void* las_ptr;

__device__ __forceinline__ void dma_1kb(const char* g, char* lds, int lane) {
    __builtin_amdgcn_global_load_lds((gas_ptr)(g + lane * 16), (las_ptr)lds, 16, 0, 0);
}

// ---------------------------------------------------------------------------
// Kernel 2: predictive phase — per-wave double-buffered DMA pipeline.
//
// R5 theory: the old one-shot block (8 cells, one vmcnt(0)+barrier, die)
// left the memory pipe idle at every block boundary: 102 us vs a ~41 us
// HBM roofline with VALUBusy=10%, hbm_pct=16% (nothing saturated).
//
// New structure: each wave owns 16 cells and only ever consumes data it
// staged itself; the mask is the single cross-wave dependency, so ONE
// __syncthreads total. Per-cell loop: issue next cell's 4x1KB DMA into the
// spare buffer, `s_waitcnt vmcnt(4)` (counted — next stays in flight, T4),
// consume current from LDS, repeat. No VMEM ops inside the loop (results
// accumulate in a register bitmask, stored once at the end) so the vmcnt
// count is exact. `lgkmcnt(0)` before each issue closes the LDS
// write-after-read hazard on the recycled buffer.
//
// Grid = 1024 blocks = 4/CU * 256 CU: fully resident, zero launch churn,
// mask staged 1024x (was 8192x). LDS = 8 KB mask + 4 waves * 2 bufs * 4 KB
// = 40960 B -> 4 blocks/CU, 64 KB DMA in flight per CU in steady state.
// ---------------------------------------------------------------------------
__global__ __launch_bounds__(256) void tm_predict_kernel(
    const int*   __restrict__ seg_pre,
    const float* __restrict__ seg_perm,
    const unsigned int* __restrict__ ws_mask,
    const unsigned char* __restrict__ ws_flags,
    float* __restrict__ out_pred,
    float* __restrict__ out_anomaly)
{
    __shared__ unsigned int mask[COLS];       // 8 KB active bitmask
    __shared__ char stage[4][2][4096];        // per wave: 2 x (2KB pre | 2KB perm)

    int tid  = threadIdx.x;
    int wave = tid >> 6;
    int lane = tid & 63;
    int base = blockIdx.x * CPB + wave * CPW; // first cell of this wave

    // ---- Prologue: prefetch cell 0, stage mask, one barrier ----
    {
        const char* gp = (const char*)(seg_pre  + (size_t)base * 512);
        const char* gq = (const char*)(seg_perm + (size_t)base * 512);
        char* L = stage[wave][0];
        dma_1kb(gp,        L,        lane);
        dma_1kb(gp + 1024, L + 1024, lane);
        dma_1kb(gq,        L + 2048, lane);
        dma_1kb(gq + 1024, L + 3072, lane);
    }

    ((uint4*)mask)[tid]       = ((const uint4*)ws_mask)[tid];
    ((uint4*)mask)[tid + 256] = ((const uint4*)ws_mask)[tid + 256];

    __syncthreads();   // mask ready; implicit vmcnt(0) also completes buffer 0

    // ---- Main loop: 16 cells, double-buffered, barrier-free ----
    unsigned pmask = 0;
    #pragma unroll
    for (int i = 0; i < CPW; ++i) {
        char* L = stage[wave][i & 1];

        if (i + 1 < CPW) {
            // Recycled buffer was ds_read at iter i-1: drain DS queue before
            // the DMA can overwrite it (architecturally safe, ~free here).
            asm volatile("s_waitcnt lgkmcnt(0)" ::: "memory");
            const char* gp = (const char*)(seg_pre  + (size_t)(base + i + 1) * 512);
            const char* gq = (const char*)(seg_perm + (size_t)(base + i + 1) * 512);
            char* Ln = stage[wave][(i + 1) & 1];
            dma_1kb(gp,        Ln,        lane);
            dma_1kb(gp + 1024, Ln + 1024, lane);
            dma_1kb(gq,        Ln + 2048, lane);
            dma_1kb(gq + 1024, Ln + 3072, lane);
            __builtin_amdgcn_sched_barrier(0);
            // Exactly 8 VMEM outstanding: oldest 4 = current buffer.
            asm volatile("s_waitcnt vmcnt(4)" ::: "memory");
        } else {
            asm volatile("s_waitcnt vmcnt(0)" ::: "memory");
        }

        const int4*   pl = (const int4*)  L;
        const float4* ql = (const float4*)(L + 2048);

        int4   p0 = pl[lane], p1 = pl[lane + 64];
        float4 q0 = ql[lane], q1 = ql[lane + 64];

        int c0 = 0, c1 = 0;
        c0 += (q0.x >= 0.5f && ((mask[(unsigned)p0.x >> 5] >> ((unsigned)p0.x & 31u)) & 1u)) ? 1 : 0;
        c0 += (q0.y >= 0.5f && ((mask[(unsigned)p0.y >> 5] >> ((unsigned)p0.y & 31u)) & 1u)) ? 1 : 0;
        c0 += (q0.z >= 0.5f && ((mask[(unsigned)p0.z >> 5] >> ((unsigned)p0.z & 31u)) & 1u)) ? 1 : 0;
        c0 += (q0.w >= 0.5f && ((mask[(unsigned)p0.w >> 5] >> ((unsigned)p0.w & 31u)) & 1u)) ? 1 : 0;
        c1 += (q1.x >= 0.5f && ((mask[(unsigned)p1.x >> 5] >> ((unsigned)p1.x & 31u)) & 1u)) ? 1 : 0;
        c1 += (q1.y >= 0.5f && ((mask[(unsigned)p1.y >> 5] >> ((unsigned)p1.y & 31u)) & 1u)) ? 1 : 0;
        c1 += (q1.z >= 0.5f && ((mask[(unsigned)p1.z >> 5] >> ((unsigned)p1.z & 31u)) & 1u)) ? 1 : 0;
        c1 += (q1.w >= 0.5f && ((mask[(unsigned)p1.w >> 5] >> ((unsigned)p1.w & 31u)) & 1u)) ? 1 : 0;

        // lane handles int4 elems lane and lane+64 of 128; elem e -> segment e/8.
        // Pack, 8-lane butterfly ADD (full segment counts), unpack+max,
        // butterfly MAX across groups -> every lane holds the cell's best count.
        int v = c0 | (c1 << 16);
        v += __shfl_xor(v, 1, 64);
        v += __shfl_xor(v, 2, 64);
        v += __shfl_xor(v, 4, 64);
        int m = max(v & 0xffff, v >> 16);
        m = max(m, __shfl_xor(m, 8, 64));
        m = max(m, __shfl_xor(m, 16, 64));
        m = max(m, __shfl_xor(m, 32, 64));

        pmask |= (m >= THRESH) ? (1u << i) : 0u;
    }

    // ---- Single coalesced result store per wave (no VMEM inside loop) ----
    if (lane < CPW)
        out_pred[base + lane] = ((pmask >> lane) & 1u) ? 1.0f : 0.0f;

    // ---- Anomaly: block 0 / wave 0 reduces 2048 flag bytes (no LDS) ----
    if (blockIdx.x == 0 && tid < 64) {
        const unsigned int* f = (const unsigned int*)ws_flags;
        int na = 0, np = 0;
        #pragma unroll
        for (int i = 0; i < 8; ++i) {
            unsigned w = f[tid * 8 + i];
            na += __popc(w & 0x01010101u);
            np += __popc(w & 0x02020202u);
        }
        int v = na | (np << 16);
        v += __shfl_xor(v, 1, 64);
        v += __shfl_xor(v, 2, 64);
        v += __shfl_xor(v, 4, 64);
        v += __shfl_xor(v, 8, 64);
        v += __shfl_xor(v, 16, 64);
        v += __shfl_xor(v, 32, 64);
        if (tid == 0) {
            int NA = v & 0xffff, NP = v >> 16;
            *out_anomaly = 1.0f - (float)NP / (float)(NA > 1 ? NA : 1);
        }
    }
}

// ---------------------------------------------------------------------------
// Inputs (setup_inputs order):
//   d_in[0] active_columns  f32 [2048]
//   d_in[1] prev_active     f32 [65536]   (unused by the reference)
//   d_in[2] prev_predictive f32 [65536]
//   d_in[3] seg_pre         i32 [65536*16*32]
//   d_in[4] seg_perm        f32 [65536*16*32]
// Output: f32 [65536 active | 65536 predictive | 1 anomaly]
// Workspace: ws[0..2047] u32 bitmask, then 2048 u8 column flags
// ---------------------------------------------------------------------------
extern "C" void kernel_launch(void* const* d_in, const int* in_sizes, int n_in,
                              void* d_out, int out_size, void* d_ws, size_t ws_size,
                              hipStream_t stream) {
    const float* active_columns  = (const float*)d_in[0];
    const float* prev_predictive = (const float*)d_in[2];
    const int*   seg_pre         = (const int*)d_in[3];
    const float* seg_perm        = (const float*)d_in[4];
    float* out = (float*)d_out;

    unsigned int*  ws_mask  = (unsigned int*)d_ws;
    unsigned char* ws_flags = (unsigned char*)d_ws + COLS * sizeof(unsigned int);

    tm_active_kernel<<<NCELLS / 256, 256, 0, stream>>>(
        active_columns, prev_predictive, out, ws_mask, ws_flags);

    tm_predict_kernel<<<PREDICT_GRID, 256, 0, stream>>>(
        seg_pre, seg_perm, ws_mask, ws_flags,
        out + NCELLS, out + 2 * NCELLS);
}

// Round 2
// 276.386 us; speedup vs baseline: 1.0387x; 1.0387x over previous
//
#include <hip/hip_runtime.h>

// Problem constants (from reference)
#define COLS    2048
#define CPC     32          // cells per column == 32 bits -> one word per column
#define NCELLS  65536       // COLS * CPC
#define SEGS    16
#define SYN     32
#define THRESH  13

#define CPW     16                     // cells per wave (pipelined)
#define CPB     (4 * CPW)              // 64 cells per block (4 waves)
#define PREDICT_GRID (NCELLS / CPB)    // 1024 blocks -> 4/CU

// ---------------------------------------------------------------------------
// Kernel 1: active-cell phase (unchanged — correct, tiny, atomic-free).
// ---------------------------------------------------------------------------
__global__ __launch_bounds__(256) void tm_active_kernel(
    const float* __restrict__ active_columns,
    const float* __restrict__ prev_predictive,
    float* __restrict__ out_active,
    unsigned int* __restrict__ ws_mask,
    unsigned char* __restrict__ ws_flags)
{
    int n = blockIdx.x * 256 + threadIdx.x;   // cell index, grid is exact
    int c = n >> 5;                            // column
    int j = n & 31;                            // cell within column
    int lane = threadIdx.x & 63;

    bool predbit    = prev_predictive[n] > 0.0f;
    bool col_active = active_columns[c] > 0.0f;

    unsigned long long pb = __ballot(predbit);
    unsigned int colmask = (lane < 32) ? (unsigned int)pb : (unsigned int)(pb >> 32);
    bool has_pred = (colmask != 0u);

    bool active = col_active && (has_pred ? predbit : true);
    out_active[n] = active ? 1.0f : 0.0f;

    unsigned long long ab = __ballot(active);
    if (lane == 0)  ws_mask[c] = (unsigned int)ab;
    if (lane == 32) ws_mask[c] = (unsigned int)(ab >> 32);

    if (j == 0)
        ws_flags[c] = (unsigned char)((col_active ? 1 : 0) |
                                      ((col_active && has_pred) ? 2 : 0));
}

// ---------------------------------------------------------------------------
// Async global->LDS DMA, 1 KB per wave-instruction: lane i's 16 B from
// g + i*16 lands at lds + i*16 (wave-uniform LDS base + lane*size — m104).
//
// R6: aux (CPol) bit1 = nt on gfx950. seg_perm is streamed non-temporal so
// it does NOT allocate in the 256 MB L3; seg_pre keeps default policy so its
// 128 MB stays L3-resident across dispatches. Theory: the 256 MB combined
// stream == L3 capacity -> LRU capacity thrash (49% hit, both supply paths
// throttled to ~1.2 TB/s each). Splitting policy gives HBM (perm) and L3
// (pre) each their own full-rate path.
// ---------------------------------------------------------------------------
typedef const __attribute__((address_space(1))) void* gas_ptr;
typedef __attribute__((address_space(3)))       void* las_ptr;

__device__ __forceinline__ void dma_1kb(const char* g, char* lds, int lane) {
    __builtin_amdgcn_global_load_lds((gas_ptr)(g + lane * 16), (las_ptr)lds, 16, 0, 0);
}
__device__ __forceinline__ void dma_1kb_nt(const char* g, char* lds, int lane) {
    __builtin_amdgcn_global_load_lds((gas_ptr)(g + lane * 16), (las_ptr)lds, 16, 0, 2);
}

// ---------------------------------------------------------------------------
// Kernel 2: predictive phase — per-wave double-buffered DMA pipeline.
// Structure identical to R5 (neutral but correct, keeps CU-side concurrency
// maximal); only the cache policy of the perm stream changed.
// ---------------------------------------------------------------------------
__global__ __launch_bounds__(256) void tm_predict_kernel(
    const int*   __restrict__ seg_pre,
    const float* __restrict__ seg_perm,
    const unsigned int* __restrict__ ws_mask,
    const unsigned char* __restrict__ ws_flags,
    float* __restrict__ out_pred,
    float* __restrict__ out_anomaly)
{
    __shared__ unsigned int mask[COLS];       // 8 KB active bitmask
    __shared__ char stage[4][2][4096];        // per wave: 2 x (2KB pre | 2KB perm)

    int tid  = threadIdx.x;
    int wave = tid >> 6;
    int lane = tid & 63;
    int base = blockIdx.x * CPB + wave * CPW; // first cell of this wave

    // ---- Prologue: prefetch cell 0, stage mask, one barrier ----
    {
        const char* gp = (const char*)(seg_pre  + (size_t)base * 512);
        const char* gq = (const char*)(seg_perm + (size_t)base * 512);
        char* L = stage[wave][0];
        dma_1kb   (gp,        L,        lane);
        dma_1kb   (gp + 1024, L + 1024, lane);
        dma_1kb_nt(gq,        L + 2048, lane);
        dma_1kb_nt(gq + 1024, L + 3072, lane);
    }

    ((uint4*)mask)[tid]       = ((const uint4*)ws_mask)[tid];
    ((uint4*)mask)[tid + 256] = ((const uint4*)ws_mask)[tid + 256];

    __syncthreads();   // mask ready; implicit vmcnt(0) also completes buffer 0

    // ---- Main loop: 16 cells, double-buffered, barrier-free ----
    unsigned pmask = 0;
    #pragma unroll
    for (int i = 0; i < CPW; ++i) {
        char* L = stage[wave][i & 1];

        if (i + 1 < CPW) {
            // Recycled buffer was ds_read at iter i-1: drain DS queue before
            // the DMA can overwrite it.
            asm volatile("s_waitcnt lgkmcnt(0)" ::: "memory");
            const char* gp = (const char*)(seg_pre  + (size_t)(base + i + 1) * 512);
            const char* gq = (const char*)(seg_perm + (size_t)(base + i + 1) * 512);
            char* Ln = stage[wave][(i + 1) & 1];
            dma_1kb   (gp,        Ln,        lane);
            dma_1kb   (gp + 1024, Ln + 1024, lane);
            dma_1kb_nt(gq,        Ln + 2048, lane);
            dma_1kb_nt(gq + 1024, Ln + 3072, lane);
            __builtin_amdgcn_sched_barrier(0);
            // Exactly 8 VMEM outstanding: oldest 4 = current buffer.
            asm volatile("s_waitcnt vmcnt(4)" ::: "memory");
        } else {
            asm volatile("s_waitcnt vmcnt(0)" ::: "memory");
        }

        const int4*   pl = (const int4*)  L;
        const float4* ql = (const float4*)(L + 2048);

        int4   p0 = pl[lane], p1 = pl[lane + 64];
        float4 q0 = ql[lane], q1 = ql[lane + 64];

        int c0 = 0, c1 = 0;
        c0 += (q0.x >= 0.5f && ((mask[(unsigned)p0.x >> 5] >> ((unsigned)p0.x & 31u)) & 1u)) ? 1 : 0;
        c0 += (q0.y >= 0.5f && ((mask[(unsigned)p0.y >> 5] >> ((unsigned)p0.y & 31u)) & 1u)) ? 1 : 0;
        c0 += (q0.z >= 0.5f && ((mask[(unsigned)p0.z >> 5] >> ((unsigned)p0.z & 31u)) & 1u)) ? 1 : 0;
        c0 += (q0.w >= 0.5f && ((mask[(unsigned)p0.w >> 5] >> ((unsigned)p0.w & 31u)) & 1u)) ? 1 : 0;
        c1 += (q1.x >= 0.5f && ((mask[(unsigned)p1.x >> 5] >> ((unsigned)p1.x & 31u)) & 1u)) ? 1 : 0;
        c1 += (q1.y >= 0.5f && ((mask[(unsigned)p1.y >> 5] >> ((unsigned)p1.y & 31u)) & 1u)) ? 1 : 0;
        c1 += (q1.z >= 0.5f && ((mask[(unsigned)p1.z >> 5] >> ((unsigned)p1.z & 31u)) & 1u)) ? 1 : 0;
        c1 += (q1.w >= 0.5f && ((mask[(unsigned)p1.w >> 5] >> ((unsigned)p1.w & 31u)) & 1u)) ? 1 : 0;

        // lane handles int4 elems lane and lane+64 of 128; elem e -> segment e/8.
        // Pack, 8-lane butterfly ADD (full segment counts), unpack+max,
        // butterfly MAX across groups -> every lane holds the cell's best count.
        int v = c0 | (c1 << 16);
        v += __shfl_xor(v, 1, 64);
        v += __shfl_xor(v, 2, 64);
        v += __shfl_xor(v, 4, 64);
        int m = max(v & 0xffff, v >> 16);
        m = max(m, __shfl_xor(m, 8, 64));
        m = max(m, __shfl_xor(m, 16, 64));
        m = max(m, __shfl_xor(m, 32, 64));

        pmask |= (m >= THRESH) ? (1u << i) : 0u;
    }

    // ---- Single coalesced result store per wave (no VMEM inside loop) ----
    if (lane < CPW)
        out_pred[base + lane] = ((pmask >> lane) & 1u) ? 1.0f : 0.0f;

    // ---- Anomaly: block 0 / wave 0 reduces 2048 flag bytes (no LDS) ----
    if (blockIdx.x == 0 && tid < 64) {
        const unsigned int* f = (const unsigned int*)ws_flags;
        int na = 0, np = 0;
        #pragma unroll
        for (int i = 0; i < 8; ++i) {
            unsigned w = f[tid * 8 + i];
            na += __popc(w & 0x01010101u);
            np += __popc(w & 0x02020202u);
        }
        int v = na | (np << 16);
        v += __shfl_xor(v, 1, 64);
        v += __shfl_xor(v, 2, 64);
        v += __shfl_xor(v, 4, 64);
        v += __shfl_xor(v, 8, 64);
        v += __shfl_xor(v, 16, 64);
        v += __shfl_xor(v, 32, 64);
        if (tid == 0) {
            int NA = v & 0xffff, NP = v >> 16;
            *out_anomaly = 1.0f - (float)NP / (float)(NA > 1 ? NA : 1);
        }
    }
}

// ---------------------------------------------------------------------------
// Inputs (setup_inputs order):
//   d_in[0] active_columns  f32 [2048]
//   d_in[1] prev_active     f32 [65536]   (unused by the reference)
//   d_in[2] prev_predictive f32 [65536]
//   d_in[3] seg_pre         i32 [65536*16*32]
//   d_in[4] seg_perm        f32 [65536*16*32]
// Output: f32 [65536 active | 65536 predictive | 1 anomaly]
// Workspace: ws[0..2047] u32 bitmask, then 2048 u8 column flags
// ---------------------------------------------------------------------------
extern "C" void kernel_launch(void* const* d_in, const int* in_sizes, int n_in,
                              void* d_out, int out_size, void* d_ws, size_t ws_size,
                              hipStream_t stream) {
    const float* active_columns  = (const float*)d_in[0];
    const float* prev_predictive = (const float*)d_in[2];
    const int*   seg_pre         = (const int*)d_in[3];
    const float* seg_perm        = (const float*)d_in[4];
    float* out = (float*)d_out;

    unsigned int*  ws_mask  = (unsigned int*)d_ws;
    unsigned char* ws_flags = (unsigned char*)d_ws + COLS * sizeof(unsigned int);

    tm_active_kernel<<<NCELLS / 256, 256, 0, stream>>>(
        active_columns, prev_predictive, out, ws_mask, ws_flags);

    tm_predict_kernel<<<PREDICT_GRID, 256, 0, stream>>>(
        seg_pre, seg_perm, ws_mask, ws_flags,
        out + NCELLS, out + 2 * NCELLS);
}

// Round 3
// 273.646 us; speedup vs baseline: 1.0491x; 1.0100x over previous
//
#include <hip/hip_runtime.h>

// Problem constants (from reference)
#define COLS    2048
#define CPC     32          // cells per column == 32 bits -> one word per column
#define NCELLS  65536       // COLS * CPC
#define SEGS    16
#define SYN     32
#define THRESH  13

#define CPW     16                     // cells per wave
#define CPB     (4 * CPW)              // 64 cells per block (4 waves)
#define PREDICT_GRID (NCELLS / CPB)    // 1024 blocks -> 4/CU

// ---------------------------------------------------------------------------
// Kernel 1: active-cell phase (unchanged — correct, tiny, atomic-free).
// ---------------------------------------------------------------------------
__global__ __launch_bounds__(256) void tm_active_kernel(
    const float* __restrict__ active_columns,
    const float* __restrict__ prev_predictive,
    float* __restrict__ out_active,
    unsigned int* __restrict__ ws_mask,
    unsigned char* __restrict__ ws_flags)
{
    int n = blockIdx.x * 256 + threadIdx.x;   // cell index, grid is exact
    int c = n >> 5;                            // column
    int j = n & 31;                            // cell within column
    int lane = threadIdx.x & 63;

    bool predbit    = prev_predictive[n] > 0.0f;
    bool col_active = active_columns[c] > 0.0f;

    unsigned long long pb = __ballot(predbit);
    unsigned int colmask = (lane < 32) ? (unsigned int)pb : (unsigned int)(pb >> 32);
    bool has_pred = (colmask != 0u);

    bool active = col_active && (has_pred ? predbit : true);
    out_active[n] = active ? 1.0f : 0.0f;

    unsigned long long ab = __ballot(active);
    if (lane == 0)  ws_mask[c] = (unsigned int)ab;
    if (lane == 32) ws_mask[c] = (unsigned int)(ab >> 32);

    if (j == 0)
        ws_flags[c] = (unsigned char)((col_active ? 1 : 0) |
                                      ((col_active && has_pred) ? 2 : 0));
}

// ---------------------------------------------------------------------------
// Kernel 2: predictive phase — pure VGPR streaming, register double-buffer.
//
// R7 theory: the LDS-DMA (global_load_lds) fill path is concurrency-capped
// per CU (~1 KB retired / ~170 cyc, structure-insensitive across R4-R6;
// only the nt latency cut moved it, FETCH_SIZE bit-identical). Plain
// VGPR loads proved 6.3 TB/s chip-wide (m13), 2x our 3.2 TB/s wall, and
// pre/perm have ZERO reuse (Common-mistake #7: don't LDS-stage them).
// LDS keeps only the 8 KB mask. perm = nontemporal (won +22% in R6),
// pre = default policy so L3 keeps serving it at ~100% hit.
//
// Pipeline: cells processed in pairs; while consuming pair j (registers),
// the 8 dwordx4 loads of pair j+1 are in flight (8 KB/wave outstanding;
// 16 waves/CU -> 128 KB/CU). Explicit A/B register buffers with static
// names (rule #20), loop unrolled over pairs-of-pairs so no runtime
// indexing ever touches the buffers.
// ---------------------------------------------------------------------------
typedef int   i4 __attribute__((ext_vector_type(4)));
typedef float f4 __attribute__((ext_vector_type(4)));

__device__ __forceinline__ int cell_count(const unsigned int* mask,
                                          i4 p0, i4 p1, f4 q0, f4 q1)
{
    int c0 = 0, c1 = 0;
    c0 += (q0.x >= 0.5f && ((mask[(unsigned)p0.x >> 5] >> ((unsigned)p0.x & 31u)) & 1u)) ? 1 : 0;
    c0 += (q0.y >= 0.5f && ((mask[(unsigned)p0.y >> 5] >> ((unsigned)p0.y & 31u)) & 1u)) ? 1 : 0;
    c0 += (q0.z >= 0.5f && ((mask[(unsigned)p0.z >> 5] >> ((unsigned)p0.z & 31u)) & 1u)) ? 1 : 0;
    c0 += (q0.w >= 0.5f && ((mask[(unsigned)p0.w >> 5] >> ((unsigned)p0.w & 31u)) & 1u)) ? 1 : 0;
    c1 += (q1.x >= 0.5f && ((mask[(unsigned)p1.x >> 5] >> ((unsigned)p1.x & 31u)) & 1u)) ? 1 : 0;
    c1 += (q1.y >= 0.5f && ((mask[(unsigned)p1.y >> 5] >> ((unsigned)p1.y & 31u)) & 1u)) ? 1 : 0;
    c1 += (q1.z >= 0.5f && ((mask[(unsigned)p1.z >> 5] >> ((unsigned)p1.z & 31u)) & 1u)) ? 1 : 0;
    c1 += (q1.w >= 0.5f && ((mask[(unsigned)p1.w >> 5] >> ((unsigned)p1.w & 31u)) & 1u)) ? 1 : 0;

    // lane holds int4 elems lane and lane+64 of the cell's 128; elem e ->
    // segment e/8. Butterfly-ADD over the 8-lane group gives full segment
    // counts (seg g in lo, g+8 in hi), then unpack+max and butterfly-MAX.
    int v = c0 | (c1 << 16);
    v += __shfl_xor(v, 1, 64);
    v += __shfl_xor(v, 2, 64);
    v += __shfl_xor(v, 4, 64);
    int m = max(v & 0xffff, v >> 16);
    m = max(m, __shfl_xor(m, 8, 64));
    m = max(m, __shfl_xor(m, 16, 64));
    m = max(m, __shfl_xor(m, 32, 64));
    return m;
}

// Load one cell-pair (cells `cell` and `cell+1`) into 8 named vec4 regs.
// gp/gq are lane-offset bases; cell stride = 128 vec4 (512 elems * 4 B).
#define LOADPAIR(P0,P1,P2,P3,Q0,Q1,Q2,Q3, cell) do {                         \
    const i4* _p = gp + (cell) * 128;                                        \
    const f4* _q = gq + (cell) * 128;                                        \
    P0 = _p[0];   P1 = _p[64];   P2 = _p[128];  P3 = _p[192];                \
    Q0 = __builtin_nontemporal_load(_q);        Q1 = __builtin_nontemporal_load(_q + 64); \
    Q2 = __builtin_nontemporal_load(_q + 128);  Q3 = __builtin_nontemporal_load(_q + 192); \
} while (0)

__global__ __launch_bounds__(256, 4) void tm_predict_kernel(
    const int*   __restrict__ seg_pre,
    const float* __restrict__ seg_perm,
    const unsigned int* __restrict__ ws_mask,
    const unsigned char* __restrict__ ws_flags,
    float* __restrict__ out_pred,
    float* __restrict__ out_anomaly)
{
    __shared__ unsigned int mask[COLS];       // 8 KB active bitmask (only LDS)

    int tid  = threadIdx.x;
    int wave = tid >> 6;
    int lane = tid & 63;
    int base = blockIdx.x * CPB + wave * CPW; // first cell of this wave

    const i4* gp = (const i4*)(seg_pre  + (size_t)base * 512) + lane;
    const f4* gq = (const f4*)(seg_perm + (size_t)base * 512) + lane;

    // Pair register buffers (A = even pair, B = odd pair), static names only.
    i4 pA0, pA1, pA2, pA3, pB0, pB1, pB2, pB3;
    f4 qA0, qA1, qA2, qA3, qB0, qB1, qB2, qB3;

    // ---- Prologue: issue pair 0 loads, stage mask, barrier ----
    LOADPAIR(pA0,pA1,pA2,pA3,qA0,qA1,qA2,qA3, 0);

    ((uint4*)mask)[tid]       = ((const uint4*)ws_mask)[tid];
    ((uint4*)mask)[tid + 256] = ((const uint4*)ws_mask)[tid + 256];

    __syncthreads();   // mask visible to all waves

    // ---- Main loop: 8 pairs, ping-pong A/B, loads lead consumes by 1 pair ----
    unsigned pmask = 0;
    #pragma unroll
    for (int j = 0; j < 8; j += 2) {
        // consume pair j from A, pair j+1 from B; prefetch j+1 / j+2 first
        LOADPAIR(pB0,pB1,pB2,pB3,qB0,qB1,qB2,qB3, 2*(j+1));

        int m0 = cell_count(mask, pA0, pA1, qA0, qA1);
        int m1 = cell_count(mask, pA2, pA3, qA2, qA3);
        pmask |= (m0 >= THRESH) ? (1u << (2*j))     : 0u;
        pmask |= (m1 >= THRESH) ? (1u << (2*j + 1)) : 0u;

        if (j + 2 < 8)
            LOADPAIR(pA0,pA1,pA2,pA3,qA0,qA1,qA2,qA3, 2*(j+2));

        int m2 = cell_count(mask, pB0, pB1, qB0, qB1);
        int m3 = cell_count(mask, pB2, pB3, qB2, qB3);
        pmask |= (m2 >= THRESH) ? (1u << (2*j + 2)) : 0u;
        pmask |= (m3 >= THRESH) ? (1u << (2*j + 3)) : 0u;
    }

    // ---- Single coalesced result store per wave ----
    if (lane < CPW)
        out_pred[base + lane] = ((pmask >> lane) & 1u) ? 1.0f : 0.0f;

    // ---- Anomaly: block 0 / wave 0 reduces 2048 flag bytes (no LDS) ----
    if (blockIdx.x == 0 && tid < 64) {
        const unsigned int* f = (const unsigned int*)ws_flags;
        int na = 0, np = 0;
        #pragma unroll
        for (int i = 0; i < 8; ++i) {
            unsigned w = f[tid * 8 + i];
            na += __popc(w & 0x01010101u);
            np += __popc(w & 0x02020202u);
        }
        int v = na | (np << 16);
        v += __shfl_xor(v, 1, 64);
        v += __shfl_xor(v, 2, 64);
        v += __shfl_xor(v, 4, 64);
        v += __shfl_xor(v, 8, 64);
        v += __shfl_xor(v, 16, 64);
        v += __shfl_xor(v, 32, 64);
        if (tid == 0) {
            int NA = v & 0xffff, NP = v >> 16;
            *out_anomaly = 1.0f - (float)NP / (float)(NA > 1 ? NA : 1);
        }
    }
}

// ---------------------------------------------------------------------------
// Inputs (setup_inputs order):
//   d_in[0] active_columns  f32 [2048]
//   d_in[1] prev_active     f32 [65536]   (unused by the reference)
//   d_in[2] prev_predictive f32 [65536]
//   d_in[3] seg_pre         i32 [65536*16*32]
//   d_in[4] seg_perm        f32 [65536*16*32]
// Output: f32 [65536 active | 65536 predictive | 1 anomaly]
// Workspace: ws[0..2047] u32 bitmask, then 2048 u8 column flags
// ---------------------------------------------------------------------------
extern "C" void kernel_launch(void* const* d_in, const int* in_sizes, int n_in,
                              void* d_out, int out_size, void* d_ws, size_t ws_size,
                              hipStream_t stream) {
    const float* active_columns  = (const float*)d_in[0];
    const float* prev_predictive = (const float*)d_in[2];
    const int*   seg_pre         = (const int*)d_in[3];
    const float* seg_perm        = (const float*)d_in[4];
    float* out = (float*)d_out;

    unsigned int*  ws_mask  = (unsigned int*)d_ws;
    unsigned char* ws_flags = (unsigned char*)d_ws + COLS * sizeof(unsigned int);

    tm_active_kernel<<<NCELLS / 256, 256, 0, stream>>>(
        active_columns, prev_predictive, out, ws_mask, ws_flags);

    tm_predict_kernel<<<PREDICT_GRID, 256, 0, stream>>>(
        seg_pre, seg_perm, ws_mask, ws_flags,
        out + NCELLS, out + 2 * NCELLS);
}